// Round 1
// baseline (30928.333 us; speedup 1.0000x reference)
//
#include <hip/hip_runtime.h>

// ============================================================================
// 2-layer tanh RNN, B=32, S=2048, D=H=O=512.
//   Phase kernel: persistent, 32 WGs, weights resident in VGPRs (bf16),
//     one flag-barrier per timestep, layer1 lags layer0 by one phase.
//   h passed between WGs as bf16 hi+lo (fp32-split) through a ws ring.
//   rnn_out (h1) written fp32 straight into d_out; second kernel applies
//     w_out in-place (stage rows to LDS first).
// ============================================================================

typedef short v8s __attribute__((ext_vector_type(8)));
typedef float v4f __attribute__((ext_vector_type(4)));

#define B_  32
#define S_  2048
#define DH  512
#define NWG 32            // 16 layer-0 WGs + 16 layer-1 WGs

// ws layout (bytes)
#define FLAGS_OFF 0                       // 64 ints
#define BIAS_OFF  1024                    // [2][512] f32  (b_ih + b_hh)
#define H0_OFF    8192                    // ring: 4 slots x (hi[32][512] + lo[32][512]) ushort
#define H1_OFF    (8192 + 262144)
#define WBF_OFF   (8192 + 524288)         // w_out bf16 [512][512]
#define SLOT_U    32768                   // ushorts per ring slot (hi+lo)
#define LO_U      16384                   // lo half offset within slot (ushorts)

static __device__ __forceinline__ unsigned short f2bf(float f) {  // RNE f32->bf16
  unsigned int u = __builtin_bit_cast(unsigned int, f);
  u += 0x7fffu + ((u >> 16) & 1u);
  return (unsigned short)(u >> 16);
}
static __device__ __forceinline__ float bf2f(unsigned short h) {
  return __builtin_bit_cast(float, ((unsigned int)h) << 16);
}
static __device__ __forceinline__ v8s pack8(float4 f0, float4 f1) {
  v8s r;
  r[0] = (short)f2bf(f0.x); r[1] = (short)f2bf(f0.y);
  r[2] = (short)f2bf(f0.z); r[3] = (short)f2bf(f0.w);
  r[4] = (short)f2bf(f1.x); r[5] = (short)f2bf(f1.y);
  r[6] = (short)f2bf(f1.z); r[7] = (short)f2bf(f1.w);
  return r;
}

// ---------------------------------------------------------------------------
__global__ void rnn_init(const float* __restrict__ hidden,  // [2][32][512]
                         const float* __restrict__ b_ih,    // [2][512]
                         const float* __restrict__ b_hh,    // [2][512]
                         const float* __restrict__ w_out,   // [512][512]
                         int* __restrict__ flags,
                         float* __restrict__ bias,
                         unsigned short* __restrict__ h0ring,
                         unsigned short* __restrict__ h1ring,
                         unsigned short* __restrict__ wbf) {
  int i = blockIdx.x * blockDim.x + threadIdx.x;
  int nth = gridDim.x * blockDim.x;
  for (int t = i; t < 64; t += nth) flags[t] = 0;
  for (int t = i; t < 1024; t += nth) bias[t] = b_ih[t] + b_hh[t];
  for (int t = i; t < 2 * B_ * DH; t += nth) {     // hidden -> ring slot 3
    int l = t >> 14;
    int off = t & 16383;                            // b*512 + f
    float v = hidden[t];
    unsigned short hv = f2bf(v);
    unsigned short lv = f2bf(v - bf2f(hv));
    unsigned short* ring = l ? h1ring : h0ring;
    ring[3 * SLOT_U + off] = hv;
    ring[3 * SLOT_U + LO_U + off] = lv;
  }
  for (int t = i; t < 512 * 512; t += nth) wbf[t] = f2bf(w_out[t]);
}

// ---------------------------------------------------------------------------
// Persistent recurrent kernel. wg<16: layer0 (owns h0 rows), wg>=16: layer1.
// Wave roles within a 512-thread WG: wid = m*4 + s*2 + n
//   m: batch half (16 batches), s: K half (512 of K=1024), n: 16-feature block
__global__ __launch_bounds__(512) void rnn_phase2(
    const float* __restrict__ x,      // [32][2048][512]
    const float* __restrict__ w_ih,   // [2][512][512]
    const float* __restrict__ w_hh,   // [2][512][512]
    const float* __restrict__ bias,   // ws [2][512]
    unsigned short* __restrict__ h0ring,
    unsigned short* __restrict__ h1ring,
    int* __restrict__ flags,
    float* __restrict__ dout) {       // [32][2048][512] (rnn_out staging)
  const int wg = blockIdx.x;
  const int layer = wg >> 4;
  const int row_base = (wg & 15) * 32;

  const int tid = threadIdx.x;
  const int wid = tid >> 6;
  const int lane = tid & 63;
  const int m = wid >> 2, s = (wid >> 1) & 1, n = wid & 1;
  const int l15 = lane & 15;
  const int kq = (lane >> 4) * 8;     // k offset within each 32-wide K step
  const int rowA = m * 16 + l15;      // batch index (A-frag row / D row)
  const int rowW = row_base + n * 16 + l15;  // output feature (B-frag row / D col)

  // --- resident weights: 16 K-steps x 8 bf16 = 64 VGPRs -------------------
  v8s wfrag[16];
  {
    const float* wsrc = (s ? w_hh : w_ih) + ((size_t)layer * 512 + rowW) * 512;
    #pragma unroll
    for (int ks = 0; ks < 16; ++ks) {
      int kk = ks * 32 + kq;
      wfrag[ks] = pack8(*(const float4*)(wsrc + kk), *(const float4*)(wsrc + kk + 4));
    }
  }
  const float biasv = bias[layer * 512 + row_base + n * 16 + l15];
  const bool is_xwave = (layer == 0) && (s == 0);

  // x prefetch registers (only meaningful for x-waves); x is immutable so
  // loads may safely be in flight across the barrier.
  float4 xpf[32];
  if (is_xwave) {
    const float* xb0 = x + ((size_t)rowA * S_ + 0) * DH;
    #pragma unroll
    for (int ks = 0; ks < 16; ++ks) {
      int kk = ks * 32 + kq;
      xpf[2 * ks]     = *(const float4*)(xb0 + kk);
      xpf[2 * ks + 1] = *(const float4*)(xb0 + kk + 4);
    }
  }

  __shared__ v4f lds_p[4 * 64];   // partial C from s==1 waves

  for (int p = 0; p <= S_; ++p) {
    const bool active = (layer == 0) ? (p < S_) : (p >= 1);
    v4f acc = {0.f, 0.f, 0.f, 0.f};

    if (active) {
      if (is_xwave) {
        int pft = (p + 1 < S_) ? (p + 1) : (S_ - 1);       // guard OOB
        const float* xbn = x + ((size_t)rowA * S_ + pft) * DH;
        v4f a0 = {0.f,0.f,0.f,0.f}, a1 = {0.f,0.f,0.f,0.f};
        #pragma unroll
        for (int ks = 0; ks < 16; ++ks) {
          int kk = ks * 32 + kq;
          v8s a = pack8(xpf[2 * ks], xpf[2 * ks + 1]);
          xpf[2 * ks]     = *(const float4*)(xbn + kk);     // prefetch t+1
          xpf[2 * ks + 1] = *(const float4*)(xbn + kk + 4);
          if (ks & 1) a1 = __builtin_amdgcn_mfma_f32_16x16x32_bf16(a, wfrag[ks], a1, 0, 0, 0);
          else        a0 = __builtin_amdgcn_mfma_f32_16x16x32_bf16(a, wfrag[ks], a0, 0, 0, 0);
        }
        acc = a0 + a1;
      } else {
        const unsigned short* ring;
        int slot;
        if (layer == 0)      { ring = h0ring; slot = (p - 1) & 3; }  // s==1: h0
        else if (s == 0)     { ring = h0ring; slot = (p - 1) & 3; }  // h0 input
        else                 { ring = h1ring; slot = (p - 2) & 3; }  // h1 recur
        const unsigned short* hi = ring + (size_t)slot * SLOT_U + (size_t)rowA * 512;
        const unsigned short* lo = hi + LO_U;
        v4f ah = {0.f,0.f,0.f,0.f}, al = {0.f,0.f,0.f,0.f};
        #pragma unroll
        for (int ks = 0; ks < 16; ++ks) {
          int kk = ks * 32 + kq;
          v8s vhi = *(const v8s*)(hi + kk);
          v8s vlo = *(const v8s*)(lo + kk);
          ah = __builtin_amdgcn_mfma_f32_16x16x32_bf16(vhi, wfrag[ks], ah, 0, 0, 0);
          al = __builtin_amdgcn_mfma_f32_16x16x32_bf16(vlo, wfrag[ks], al, 0, 0, 0);
        }
        acc = ah + al;
      }
      if (s == 1) lds_p[(m * 2 + n) * 64 + lane] = acc;
    }
    __syncthreads();

    if (active && s == 0) {
      v4f other = lds_p[(m * 2 + n) * 64 + lane];
      #pragma unroll
      for (int r = 0; r < 4; ++r) {
        float v = acc[r] + other[r] + biasv;
        float h = tanhf(v);
        unsigned short hv = f2bf(h);
        unsigned short lv = f2bf(h - bf2f(hv));
        int batch = m * 16 + (lane >> 4) * 4 + r;   // D: row=(lane>>4)*4+reg
        int feat  = row_base + n * 16 + l15;        // D: col=lane&15
        size_t off = (size_t)batch * 512 + feat;
        if (layer == 0) {
          unsigned short* dst = h0ring + (size_t)(p & 3) * SLOT_U;
          dst[off] = hv;
          dst[off + LO_U] = lv;
        } else {
          unsigned short* dst = h1ring + (size_t)((p - 1) & 3) * SLOT_U;
          dst[off] = hv;
          dst[off + LO_U] = lv;
          dout[((size_t)batch * S_ + (p - 1)) * DH + feat] = h;
        }
      }
    }
    __syncthreads();   // all stores drained to L2 before release

    if (wid == 0) {
      __builtin_amdgcn_fence(__ATOMIC_RELEASE, "agent");   // wb L2 -> L3
      if (lane == 0)
        __hip_atomic_store(&flags[wg], p + 1, __ATOMIC_RELAXED, __HIP_MEMORY_SCOPE_AGENT);
      const int target = p + 1;
      for (;;) {
        int v = (lane < NWG)
                  ? __hip_atomic_load(&flags[lane], __ATOMIC_RELAXED, __HIP_MEMORY_SCOPE_AGENT)
                  : 0x7fffffff;
        if (__all(v >= target)) break;
        __builtin_amdgcn_s_sleep(1);
      }
    }
    __syncthreads();
    __builtin_amdgcn_fence(__ATOMIC_ACQUIRE, "agent");     // inv L1/L2
  }
}

// ---------------------------------------------------------------------------
// In-place output projection: d_out rows (=h1, fp32) -> LDS bf16 (swizzled),
// then out = rows @ w_out^T + b_out overwrites the same rows.
__global__ __launch_bounds__(512) void rnn_phase3(
    float* __restrict__ dout,
    const unsigned short* __restrict__ wbf,   // [512][512] bf16
    const float* __restrict__ b_out) {
  __shared__ unsigned short lds[64 * 512];    // 64KB
  const int tid = threadIdx.x;
  const int wid = tid >> 6;
  const int lane = tid & 63;
  const size_t row0 = (size_t)blockIdx.x * 64;

  // stage 64 rows, fp32 -> bf16, XOR-swizzled to kill ds_read_b128 conflicts
  #pragma unroll
  for (int it = 0; it < 8; ++it) {
    int c = it * 512 + tid;           // 4096 chunks of 8 cols
    int row = c >> 6;
    int col8 = c & 63;
    const float4* src = (const float4*)(dout + (row0 + row) * DH + col8 * 8);
    float4 f0 = src[0], f1 = src[1];
    v8s t = pack8(f0, f1);
    int byteoff = row * 1024 + ((col8 * 16) ^ ((row & 7) << 4));
    *(v8s*)((char*)lds + byteoff) = t;
  }
  __syncthreads();

  const int l15 = lane & 15;
  const int kq = (lane >> 4) * 8;

  for (int nt = wid; nt < 32; nt += 8) {      // 16-wide output-feature tiles
    v4f acc[4];
    #pragma unroll
    for (int mt = 0; mt < 4; ++mt) acc[mt] = (v4f){0.f, 0.f, 0.f, 0.f};
    const unsigned short* wb = wbf + (size_t)(nt * 16 + l15) * 512;
    #pragma unroll
    for (int ks = 0; ks < 16; ++ks) {
      int kk = ks * 32 + kq;
      v8s bfrag = *(const v8s*)(wb + kk);
      #pragma unroll
      for (int mt = 0; mt < 4; ++mt) {
        int row = mt * 16 + l15;
        int byteoff = row * 1024 + ((kk * 2) ^ ((row & 7) << 4));
        v8s afrag = *(const v8s*)((char*)lds + byteoff);
        acc[mt] = __builtin_amdgcn_mfma_f32_16x16x32_bf16(afrag, bfrag, acc[mt], 0, 0, 0);
      }
    }
    float bo = b_out[nt * 16 + l15];
    #pragma unroll
    for (int mt = 0; mt < 4; ++mt)
      #pragma unroll
      for (int r = 0; r < 4; ++r) {
        int row = mt * 16 + (lane >> 4) * 4 + r;
        int col = nt * 16 + l15;
        dout[(row0 + row) * DH + col] = acc[mt][r] + bo;
      }
  }
}

// ---------------------------------------------------------------------------
extern "C" void kernel_launch(void* const* d_in, const int* in_sizes, int n_in,
                              void* d_out, int out_size, void* d_ws, size_t ws_size,
                              hipStream_t stream) {
  const float* x      = (const float*)d_in[0];
  const float* hidden = (const float*)d_in[1];
  const float* w_ih   = (const float*)d_in[2];
  const float* w_hh   = (const float*)d_in[3];
  const float* b_ih   = (const float*)d_in[4];
  const float* b_hh   = (const float*)d_in[5];
  const float* w_out  = (const float*)d_in[6];
  const float* b_out  = (const float*)d_in[7];
  float* out = (float*)d_out;

  char* wsb = (char*)d_ws;
  int* flags            = (int*)(wsb + FLAGS_OFF);
  float* bias           = (float*)(wsb + BIAS_OFF);
  unsigned short* h0ring = (unsigned short*)(wsb + H0_OFF);
  unsigned short* h1ring = (unsigned short*)(wsb + H1_OFF);
  unsigned short* wbf    = (unsigned short*)(wsb + WBF_OFF);

  rnn_init<<<256, 256, 0, stream>>>(hidden, b_ih, b_hh, w_out,
                                    flags, bias, h0ring, h1ring, wbf);
  rnn_phase2<<<NWG, 512, 0, stream>>>(x, w_ih, w_hh, bias,
                                      h0ring, h1ring, flags, out);
  rnn_phase3<<<(B_ * S_) / 64, 512, 0, stream>>>(out, wbf, b_out);
}

// Round 2
// 22061.171 us; speedup vs baseline: 1.4019x; 1.4019x over previous
//
#include <hip/hip_runtime.h>

// ============================================================================
// 2-layer tanh RNN, B=32, S=2048, D=H=O=512.
//  r1: removed agent fences (they emitted per-step full-L2 writeback+inv).
//      Cross-WG data now uses cache-bypassing sc0/sc1 loads/stores + vmcnt
//      release ordering. Input GEMM (x @ w_ih0^T + biases) hoisted out of the
//      recurrent loop into a bulk kernel writing Z0 into d_out; layer-1 h1
//      overwrites each Z0 slot one phase after it is consumed.
// ============================================================================

typedef short v8s __attribute__((ext_vector_type(8)));
typedef int   v4i __attribute__((ext_vector_type(4)));
typedef float v4f __attribute__((ext_vector_type(4)));

#define B_  32
#define S_  2048
#define DH  512
#define NWG 32            // 16 layer-0 WGs + 16 layer-1 WGs

// ws layout (bytes)
#define FLAGS_OFF 0                       // 64 ints
#define BIAS_OFF  1024                    // [2][512] f32  (b_ih + b_hh)
#define H0_OFF    8192                    // ring: 4 slots x (hi[32][512]+lo[32][512]) ushort
#define H1_OFF    (H0_OFF + 262144)
#define WOUT_OFF  (H0_OFF + 524288)       // w_out bf16 [512][512]
#define WIH0_OFF  (WOUT_OFF + 524288)     // w_ih[0] bf16 [512][512]
#define SLOT_U    32768                   // ushorts per ring slot (hi+lo)
#define LO_U      16384                   // lo-plane offset within slot (ushorts)

static __device__ __forceinline__ unsigned short f2bf(float f) {  // RNE
  unsigned int u = __builtin_bit_cast(unsigned int, f);
  u += 0x7fffu + ((u >> 16) & 1u);
  return (unsigned short)(u >> 16);
}
static __device__ __forceinline__ float bf2f(unsigned short h) {
  return __builtin_bit_cast(float, ((unsigned int)h) << 16);
}
static __device__ __forceinline__ v8s pack8(float4 f0, float4 f1) {
  v8s r;
  r[0] = (short)f2bf(f0.x); r[1] = (short)f2bf(f0.y);
  r[2] = (short)f2bf(f0.z); r[3] = (short)f2bf(f0.w);
  r[4] = (short)f2bf(f1.x); r[5] = (short)f2bf(f1.y);
  r[6] = (short)f2bf(f1.z); r[7] = (short)f2bf(f1.w);
  return r;
}

// ---- cache-bypassing coherent accessors (device-visible without fences) ----
static __device__ __forceinline__ v8s ld16c(const void* p) {
  v4i r;
  asm volatile("global_load_dwordx4 %0, %1, off sc0 sc1"
               : "=v"(r) : "v"(p) : "memory");
  return __builtin_bit_cast(v8s, r);
}
static __device__ __forceinline__ void st16u(void* p, unsigned short v) {
  unsigned int vv = v;
  asm volatile("global_store_short %0, %1, off sc0 sc1"
               :: "v"(p), "v"(vv) : "memory");
}
static __device__ __forceinline__ void st32u(void* p, int v) {
  asm volatile("global_store_dword %0, %1, off sc0 sc1"
               :: "v"(p), "v"(v) : "memory");
}
static __device__ __forceinline__ int ld_flag(const int* p) {
  int r;
  asm volatile("global_load_dword %0, %1, off sc0 sc1\n\ts_waitcnt vmcnt(0)"
               : "=v"(r) : "v"(p) : "memory");
  return r;
}
static __device__ __forceinline__ void wait_vm0() {
  asm volatile("s_waitcnt vmcnt(0)" ::: "memory");
}

// ---------------------------------------------------------------------------
__global__ void rnn_init(const float* __restrict__ hidden,  // [2][32][512]
                         const float* __restrict__ b_ih,    // [2][512]
                         const float* __restrict__ b_hh,    // [2][512]
                         const float* __restrict__ w_out,   // [512][512]
                         const float* __restrict__ w_ih,    // [2][512][512]
                         int* __restrict__ flags,
                         float* __restrict__ bias,
                         unsigned short* __restrict__ h0ring,
                         unsigned short* __restrict__ h1ring,
                         unsigned short* __restrict__ woutbf,
                         unsigned short* __restrict__ wih0bf) {
  int i = blockIdx.x * blockDim.x + threadIdx.x;
  int nth = gridDim.x * blockDim.x;
  for (int t = i; t < 64; t += nth) flags[t] = 0;
  for (int t = i; t < 1024; t += nth) bias[t] = b_ih[t] + b_hh[t];
  for (int t = i; t < 2 * B_ * DH; t += nth) {     // hidden -> ring slot 3
    int l = t >> 14;
    int off = t & 16383;                            // b*512 + f
    float v = hidden[t];
    unsigned short hv = f2bf(v);
    unsigned short lv = f2bf(v - bf2f(hv));
    unsigned short* ring = l ? h1ring : h0ring;
    ring[3 * SLOT_U + off] = hv;
    ring[3 * SLOT_U + LO_U + off] = lv;
  }
  for (int t = i; t < 512 * 512; t += nth) {
    woutbf[t] = f2bf(w_out[t]);
    wih0bf[t] = f2bf(w_ih[t]);                      // layer-0 input weights
  }
}

// ---------------------------------------------------------------------------
// Bulk projection: dst[r][:] = src[r][:] @ wb^T + bias   (64 rows / WG)
// Used for Z0 = x @ w_ih0^T + bias0  and the final out = h1 @ w_out^T + b_out
// (in-place capable: rows staged to LDS before dst overwrite).
__global__ __launch_bounds__(512) void proj64(
    const float* __restrict__ src,            // [65536][512] f32
    float* __restrict__ dst,                  // [65536][512] f32
    const unsigned short* __restrict__ wb,    // [512][512] bf16, row-major out-feat
    const float* __restrict__ bias) {         // [512]
  __shared__ unsigned short lds[64 * 512];    // 64KB
  const int tid = threadIdx.x;
  const int wid = tid >> 6;
  const int lane = tid & 63;
  const size_t row0 = (size_t)blockIdx.x * 64;

  #pragma unroll
  for (int it = 0; it < 8; ++it) {            // stage 64 rows f32->bf16, swizzled
    int c = it * 512 + tid;
    int row = c >> 6;
    int col8 = c & 63;
    const float4* s4 = (const float4*)(src + (row0 + row) * DH + col8 * 8);
    float4 f0 = s4[0], f1 = s4[1];
    v8s t = pack8(f0, f1);
    int byteoff = row * 1024 + ((col8 * 16) ^ ((row & 7) << 4));
    *(v8s*)((char*)lds + byteoff) = t;
  }
  __syncthreads();

  const int l15 = lane & 15;
  const int kq = (lane >> 4) * 8;

  for (int nt = wid; nt < 32; nt += 8) {
    v4f acc[4];
    #pragma unroll
    for (int mt = 0; mt < 4; ++mt) acc[mt] = (v4f){0.f, 0.f, 0.f, 0.f};
    const unsigned short* wr = wb + (size_t)(nt * 16 + l15) * 512;
    #pragma unroll
    for (int ks = 0; ks < 16; ++ks) {
      int kk = ks * 32 + kq;
      v8s bfrag = *(const v8s*)(wr + kk);
      #pragma unroll
      for (int mt = 0; mt < 4; ++mt) {
        int row = mt * 16 + l15;
        int byteoff = row * 1024 + ((kk * 2) ^ ((row & 7) << 4));
        v8s afrag = *(const v8s*)((char*)lds + byteoff);
        acc[mt] = __builtin_amdgcn_mfma_f32_16x16x32_bf16(afrag, bfrag, acc[mt], 0, 0, 0);
      }
    }
    float bo = bias[nt * 16 + l15];
    #pragma unroll
    for (int mt = 0; mt < 4; ++mt)
      #pragma unroll
      for (int r = 0; r < 4; ++r) {
        int row = mt * 16 + (lane >> 4) * 4 + r;
        int col = nt * 16 + l15;
        dst[(row0 + row) * DH + col] = acc[mt][r] + bo;
      }
  }
}

// ---------------------------------------------------------------------------
// Persistent recurrent kernel. wg<16: layer0 (h0 rows), wg>=16: layer1.
// wid = m*4 + s*2 + n. layer0: s = K-half of h0@w_hh0 (+ Z0 on s==0);
// layer1: s==0 -> h0(p)@w_ih1 (full K), s==1 -> h1(p-1)@w_hh1 (full K).
__global__ __launch_bounds__(512) void rnn_phase2(
    const float* __restrict__ z0,     // d_out: Z0, becomes h1 in-place
    const float* __restrict__ w_ih,   // [2][512][512]
    const float* __restrict__ w_hh,   // [2][512][512]
    const float* __restrict__ bias,   // ws [2][512]
    unsigned short* __restrict__ h0ring,
    unsigned short* __restrict__ h1ring,
    int* __restrict__ flags,
    float* __restrict__ dout) {
  const int wg = blockIdx.x;
  const int layer = wg >> 4;
  const int row_base = (wg & 15) * 32;

  const int tid = threadIdx.x;
  const int wid = tid >> 6;
  const int lane = tid & 63;
  const int m = wid >> 2, s = (wid >> 1) & 1, n = wid & 1;
  const int l15 = lane & 15;
  const int kq = (lane >> 4) * 8;
  const int rowA = m * 16 + l15;                 // batch (A-frag row)
  const int rowW = row_base + n * 16 + l15;      // out feature (B-frag row)
  const int q4 = (lane >> 4) * 4;                // D-layout row group

  // resident weights (bf16 fragments)
  v8s wfrag[16];
  if (layer == 0) {                              // w_hh[0], K-half per s
    const float* wsrc = w_hh + (size_t)rowW * 512;
    #pragma unroll
    for (int i = 0; i < 8; ++i) {
      int kk = (s * 8 + i) * 32 + kq;
      wfrag[i] = pack8(*(const float4*)(wsrc + kk), *(const float4*)(wsrc + kk + 4));
    }
  } else {                                       // layer 1: full K per wave
    const float* wsrc = (s ? w_hh : w_ih) + (size_t)(512 + rowW) * 512;
    #pragma unroll
    for (int i = 0; i < 16; ++i) {
      int kk = i * 32 + kq;
      wfrag[i] = pack8(*(const float4*)(wsrc + kk), *(const float4*)(wsrc + kk + 4));
    }
  }
  const float biasv = (layer == 0) ? 0.f : bias[512 + row_base + n * 16 + l15];

  // layer0/s==0: Z0 prefetch (cached loads; Z0 slot t is stable until phase t+1)
  float zpf[4];
  if (layer == 0 && s == 0) {
    #pragma unroll
    for (int r = 0; r < 4; ++r)
      zpf[r] = z0[((size_t)(m * 16 + q4 + r) * S_ + 0) * DH + rowW];
  }

  __shared__ v4f lds_p[4 * 64];

  for (int p = 0; p <= S_; ++p) {
    const bool active = (layer == 0) ? (p < S_) : (p >= 1);
    v4f acc = {0.f, 0.f, 0.f, 0.f};

    if (active) {
      if (layer == 0) {
        const unsigned short* hi =
            h0ring + (size_t)((p - 1) & 3) * SLOT_U + (size_t)rowA * 512;
        const unsigned short* lo = hi + LO_U;
        v8s hf[8], lf[8];
        #pragma unroll
        for (int i = 0; i < 8; ++i) {
          int kk = (s * 8 + i) * 32 + kq;
          hf[i] = ld16c(hi + kk);
          lf[i] = ld16c(lo + kk);
        }
        wait_vm0();
        __builtin_amdgcn_sched_barrier(0);
        v4f ah = {0.f,0.f,0.f,0.f}, al = {0.f,0.f,0.f,0.f};
        #pragma unroll
        for (int i = 0; i < 8; ++i) {
          ah = __builtin_amdgcn_mfma_f32_16x16x32_bf16(hf[i], wfrag[i], ah, 0, 0, 0);
          al = __builtin_amdgcn_mfma_f32_16x16x32_bf16(lf[i], wfrag[i], al, 0, 0, 0);
        }
        acc = ah + al;
        if (s == 0) {
          #pragma unroll
          for (int r = 0; r < 4; ++r) acc[r] += zpf[r];     // Z0[p] (+biases)
          int pn = (p + 1 < S_) ? (p + 1) : (S_ - 1);
          #pragma unroll
          for (int r = 0; r < 4; ++r)                        // prefetch Z0[p+1]
            zpf[r] = z0[((size_t)(m * 16 + q4 + r) * S_ + pn) * DH + rowW];
        }
      } else {
        const unsigned short* ring;
        int slot;
        if (s == 0) { ring = h0ring; slot = (p - 1) & 3; }   // h0 input
        else        { ring = h1ring; slot = (p - 2) & 3; }   // h1 recurrent
        const unsigned short* hi =
            ring + (size_t)slot * SLOT_U + (size_t)rowA * 512;
        const unsigned short* lo = hi + LO_U;
        v8s hf[16], lf[16];
        #pragma unroll
        for (int i = 0; i < 16; ++i) {
          int kk = i * 32 + kq;
          hf[i] = ld16c(hi + kk);
          lf[i] = ld16c(lo + kk);
        }
        wait_vm0();
        __builtin_amdgcn_sched_barrier(0);
        v4f ah = {0.f,0.f,0.f,0.f}, al = {0.f,0.f,0.f,0.f};
        #pragma unroll
        for (int i = 0; i < 16; ++i) {
          ah = __builtin_amdgcn_mfma_f32_16x16x32_bf16(hf[i], wfrag[i], ah, 0, 0, 0);
          al = __builtin_amdgcn_mfma_f32_16x16x32_bf16(lf[i], wfrag[i], al, 0, 0, 0);
        }
        acc = ah + al;
      }
      if (s == 1) lds_p[(m * 2 + n) * 64 + lane] = acc;
    }
    __syncthreads();

    if (active && s == 0) {
      v4f other = lds_p[(m * 2 + n) * 64 + lane];
      #pragma unroll
      for (int r = 0; r < 4; ++r) {
        float v = acc[r] + other[r] + biasv;
        float h = tanhf(v);
        unsigned short hv = f2bf(h);
        unsigned short lv = f2bf(h - bf2f(hv));
        int batch = m * 16 + q4 + r;
        int feat  = rowW;
        size_t off = (size_t)batch * 512 + feat;
        if (layer == 0) {
          unsigned short* dst = h0ring + (size_t)(p & 3) * SLOT_U;
          st16u(dst + off, hv);
          st16u(dst + off + LO_U, lv);
        } else {
          unsigned short* dst = h1ring + (size_t)((p - 1) & 3) * SLOT_U;
          st16u(dst + off, hv);
          st16u(dst + off + LO_U, lv);
          dout[((size_t)batch * S_ + (p - 1)) * DH + feat] = h;  // cached
        }
      }
    }
    wait_vm0();          // coherent h stores complete (globally visible)
    __syncthreads();     // ... for ALL waves of this WG

    if (tid == 0) st32u(&flags[wg], p + 1);       // release: data before flag
    if (wid == 0) {
      const int target = p + 1;
      for (;;) {
        int v = 0x7fffffff;
        if (lane < NWG) v = ld_flag(&flags[lane]);
        if (__all(v >= target)) break;
      }
    }
    __syncthreads();
    __builtin_amdgcn_sched_barrier(0);
  }
}

// ---------------------------------------------------------------------------
extern "C" void kernel_launch(void* const* d_in, const int* in_sizes, int n_in,
                              void* d_out, int out_size, void* d_ws, size_t ws_size,
                              hipStream_t stream) {
  const float* x      = (const float*)d_in[0];
  const float* hidden = (const float*)d_in[1];
  const float* w_ih   = (const float*)d_in[2];
  const float* w_hh   = (const float*)d_in[3];
  const float* b_ih   = (const float*)d_in[4];
  const float* b_hh   = (const float*)d_in[5];
  const float* w_out  = (const float*)d_in[6];
  const float* b_out  = (const float*)d_in[7];
  float* out = (float*)d_out;

  char* wsb = (char*)d_ws;
  int* flags             = (int*)(wsb + FLAGS_OFF);
  float* bias            = (float*)(wsb + BIAS_OFF);
  unsigned short* h0ring = (unsigned short*)(wsb + H0_OFF);
  unsigned short* h1ring = (unsigned short*)(wsb + H1_OFF);
  unsigned short* woutbf = (unsigned short*)(wsb + WOUT_OFF);
  unsigned short* wih0bf = (unsigned short*)(wsb + WIH0_OFF);

  rnn_init<<<256, 256, 0, stream>>>(hidden, b_ih, b_hh, w_out, w_ih,
                                    flags, bias, h0ring, h1ring, woutbf, wih0bf);
  // Z0 = x @ w_ih0^T + (b_ih0 + b_hh0)  ->  d_out
  proj64<<<(B_ * S_) / 64, 512, 0, stream>>>(x, out, wih0bf, bias);
  rnn_phase2<<<NWG, 512, 0, stream>>>(out, w_ih, w_hh, bias,
                                      h0ring, h1ring, flags, out);
  // out = h1 @ w_out^T + b_out (in-place)
  proj64<<<(B_ * S_) / 64, 512, 0, stream>>>(out, out, woutbf, b_out);
}

// Round 3
// 19708.450 us; speedup vs baseline: 1.5693x; 1.1194x over previous
//
#include <hip/hip_runtime.h>

// ============================================================================
// 2-layer tanh RNN, B=32, S=2048, D=H=O=512.
//  r2: (a) chunked ld->MFMA pipeline with counted vmcnt(8) waits (bounded
//      register liveness, 2 exposed latencies/phase); (b) split elastic
//      barrier: two MALL atomic counters, ring depth 8, L0 may run up to 7
//      steps ahead of L1; one poller wave per WG + LDS mailbox for the rest;
//      (c) one __syncthreads/phase (parity-double-buffered LDS exchange),
//      fast exp-based tanh, z0[p] loads issued at phase start.
// ============================================================================

typedef short v8s __attribute__((ext_vector_type(8)));
typedef int   v4i __attribute__((ext_vector_type(4)));
typedef float v4f __attribute__((ext_vector_type(4)));

#define B_  32
#define S_  2048
#define DH  512
#define RM  7                 // ring mask (depth 8)

// ws layout (bytes)
#define CNT0_OFF 0
#define CNT1_OFF 512
#define BIAS_OFF 1024                     // [2][512] f32 (b_ih + b_hh)
#define H0_OFF   8192                     // 8 slots x 64KB (hi[32][512]+lo[32][512])
#define H1_OFF   (H0_OFF + 8 * 65536)
#define WOUT_OFF (H1_OFF + 8 * 65536)     // w_out bf16 [512][512]
#define WIH0_OFF (WOUT_OFF + 524288)      // w_ih[0] bf16 [512][512]
#define SLOT_U   32768                    // ushorts per ring slot (hi+lo)
#define LO_U     16384                    // lo-plane offset (ushorts)

static __device__ __forceinline__ unsigned short f2bf(float f) {  // RNE
  unsigned int u = __builtin_bit_cast(unsigned int, f);
  u += 0x7fffu + ((u >> 16) & 1u);
  return (unsigned short)(u >> 16);
}
static __device__ __forceinline__ float bf2f(unsigned short h) {
  return __builtin_bit_cast(float, ((unsigned int)h) << 16);
}
static __device__ __forceinline__ v8s pack8(float4 f0, float4 f1) {
  v8s r;
  r[0] = (short)f2bf(f0.x); r[1] = (short)f2bf(f0.y);
  r[2] = (short)f2bf(f0.z); r[3] = (short)f2bf(f0.w);
  r[4] = (short)f2bf(f1.x); r[5] = (short)f2bf(f1.y);
  r[6] = (short)f2bf(f1.z); r[7] = (short)f2bf(f1.w);
  return r;
}
static __device__ __forceinline__ float fast_tanh(float v) {
  float c = fminf(15.f, fmaxf(-15.f, v));
  float e = __expf(2.f * c);
  return (e - 1.f) * __builtin_amdgcn_rcpf(e + 1.f);
}

// ---- cache-bypassing coherent accessors ------------------------------------
static __device__ __forceinline__ v8s ld16c(const void* p) {
  v4i r;
  asm volatile("global_load_dwordx4 %0, %1, off sc0 sc1"
               : "=v"(r) : "v"(p) : "memory");
  return __builtin_bit_cast(v8s, r);
}
static __device__ __forceinline__ void st16u(void* p, unsigned short v) {
  unsigned int vv = v;
  asm volatile("global_store_short %0, %1, off sc0 sc1"
               :: "v"(p), "v"(vv) : "memory");
}
static __device__ __forceinline__ int ld_flag(const int* p) {
  int r;
  asm volatile("global_load_dword %0, %1, off sc0 sc1\n\ts_waitcnt vmcnt(0)"
               : "=v"(r) : "v"(p) : "memory");
  return r;
}
static __device__ __forceinline__ void wait_vm0() {
  asm volatile("s_waitcnt vmcnt(0)" ::: "memory");
}
static __device__ __forceinline__ void spin_lds(int* g, int tgt) {
  if (tgt <= 0) return;
  while (__hip_atomic_load(g, __ATOMIC_ACQUIRE, __HIP_MEMORY_SCOPE_WORKGROUP) < tgt) {}
}

// ---------------------------------------------------------------------------
__global__ void rnn_init(const float* __restrict__ hidden,
                         const float* __restrict__ b_ih,
                         const float* __restrict__ b_hh,
                         const float* __restrict__ w_out,
                         const float* __restrict__ w_ih,
                         int* __restrict__ cnts,           // ws base (cnt0, cnt1)
                         float* __restrict__ bias,
                         unsigned short* __restrict__ h0ring,
                         unsigned short* __restrict__ h1ring,
                         unsigned short* __restrict__ woutbf,
                         unsigned short* __restrict__ wih0bf) {
  int i = blockIdx.x * blockDim.x + threadIdx.x;
  int nth = gridDim.x * blockDim.x;
  for (int t = i; t < 512; t += nth) cnts[t] = 0;      // cnt0 @0, cnt1 @128
  for (int t = i; t < 1024; t += nth) bias[t] = b_ih[t] + b_hh[t];
  for (int t = i; t < 2 * B_ * DH; t += nth) {         // hidden -> ring slot 7
    int l = t >> 14;
    int off = t & 16383;
    float v = hidden[t];
    unsigned short hv = f2bf(v);
    unsigned short lv = f2bf(v - bf2f(hv));
    unsigned short* ring = l ? h1ring : h0ring;
    ring[7 * SLOT_U + off] = hv;
    ring[7 * SLOT_U + LO_U + off] = lv;
  }
  for (int t = i; t < 512 * 512; t += nth) {
    woutbf[t] = f2bf(w_out[t]);
    wih0bf[t] = f2bf(w_ih[t]);
  }
}

// ---------------------------------------------------------------------------
// Bulk projection: dst[r][:] = src[r][:] @ wb^T + bias (64 rows/WG, in-place ok)
__global__ __launch_bounds__(512) void proj64(
    const float* __restrict__ src,
    float* __restrict__ dst,
    const unsigned short* __restrict__ wb,
    const float* __restrict__ bias) {
  __shared__ unsigned short lds[64 * 512];
  const int tid = threadIdx.x;
  const int wid = tid >> 6;
  const int lane = tid & 63;
  const size_t row0 = (size_t)blockIdx.x * 64;

  #pragma unroll
  for (int it = 0; it < 8; ++it) {
    int c = it * 512 + tid;
    int row = c >> 6;
    int col8 = c & 63;
    const float4* s4 = (const float4*)(src + (row0 + row) * DH + col8 * 8);
    float4 f0 = s4[0], f1 = s4[1];
    v8s t = pack8(f0, f1);
    int byteoff = row * 1024 + ((col8 * 16) ^ ((row & 7) << 4));
    *(v8s*)((char*)lds + byteoff) = t;
  }
  __syncthreads();

  const int l15 = lane & 15;
  const int kq = (lane >> 4) * 8;

  for (int nt = wid; nt < 32; nt += 8) {
    v4f acc[4];
    #pragma unroll
    for (int mt = 0; mt < 4; ++mt) acc[mt] = (v4f){0.f, 0.f, 0.f, 0.f};
    const unsigned short* wr = wb + (size_t)(nt * 16 + l15) * 512;
    #pragma unroll
    for (int ks = 0; ks < 16; ++ks) {
      int kk = ks * 32 + kq;
      v8s bfrag = *(const v8s*)(wr + kk);
      #pragma unroll
      for (int mt = 0; mt < 4; ++mt) {
        int row = mt * 16 + l15;
        int byteoff = row * 1024 + ((kk * 2) ^ ((row & 7) << 4));
        v8s afrag = *(const v8s*)((char*)lds + byteoff);
        acc[mt] = __builtin_amdgcn_mfma_f32_16x16x32_bf16(afrag, bfrag, acc[mt], 0, 0, 0);
      }
    }
    float bo = bias[nt * 16 + l15];
    #pragma unroll
    for (int mt = 0; mt < 4; ++mt)
      #pragma unroll
      for (int r = 0; r < 4; ++r) {
        int row = mt * 16 + (lane >> 4) * 4 + r;
        int col = nt * 16 + l15;
        dst[(row0 + row) * DH + col] = acc[mt][r] + bo;
      }
  }
}

// ---------------------------------------------------------------------------
#define ISSUE(i) do { int kk_ = (koff + (i)) * 32 + kq; \
    hf[i] = ld16c(hA + kk_); lf[i] = ld16c(lA + kk_); } while (0)
#define WAITN(N) do { asm volatile("s_waitcnt vmcnt(" #N ")" ::: "memory"); \
    __builtin_amdgcn_sched_barrier(0); } while (0)
#define SB() __builtin_amdgcn_sched_barrier(0)
#define MM(i) do { \
    ah = __builtin_amdgcn_mfma_f32_16x16x32_bf16(hf[i], wfrag[i], ah, 0, 0, 0); \
    al = __builtin_amdgcn_mfma_f32_16x16x32_bf16(lf[i], wfrag[i], al, 0, 0, 0); } while (0)

__global__ __launch_bounds__(512) void rnn_phase2(
    const float* __restrict__ z0,     // d_out: Z0 (becomes h1 in place)
    const float* __restrict__ w_ih,
    const float* __restrict__ w_hh,
    const float* __restrict__ bias,
    unsigned short* __restrict__ h0ring,
    unsigned short* __restrict__ h1ring,
    int* __restrict__ cnt0,
    int* __restrict__ cnt1,
    float* __restrict__ dout) {
  const int wg = blockIdx.x;
  const int layer = wg >> 4;
  const int row_base = (wg & 15) * 32;

  const int tid = threadIdx.x;
  const int wid = tid >> 6;
  const int lane = tid & 63;
  const int m = wid >> 2, s = (wid >> 1) & 1, n = wid & 1;
  const int l15 = lane & 15;
  const int kq = (lane >> 4) * 8;
  const int rowA = m * 16 + l15;
  const int rowW = row_base + n * 16 + l15;
  const int q4 = (lane >> 4) * 4;

  // resident weights
  v8s wfrag[16];
  if (layer == 0) {                      // w_hh[0], K-half per s
    const float* wsrc = w_hh + (size_t)rowW * 512;
    #pragma unroll
    for (int i = 0; i < 8; ++i) {
      int kk = (s * 8 + i) * 32 + kq;
      wfrag[i] = pack8(*(const float4*)(wsrc + kk), *(const float4*)(wsrc + kk + 4));
    }
  } else {                               // layer 1: full K per wave
    const float* wsrc = (s ? w_hh : w_ih) + (size_t)(512 + rowW) * 512;
    #pragma unroll
    for (int i = 0; i < 16; ++i) {
      int kk = i * 32 + kq;
      wfrag[i] = pack8(*(const float4*)(wsrc + kk), *(const float4*)(wsrc + kk + 4));
    }
  }
  const float biasv = (layer == 0) ? 0.f : bias[512 + row_base + n * 16 + l15];
  int* const cnt_own = layer ? cnt1 : cnt0;

  __shared__ v4f lds_p[2][4 * 64];
  __shared__ int g0, g1;
  if (tid == 0) { g0 = 0; g1 = 0; }
  __syncthreads();

  const int PMAX = layer ? S_ : (S_ - 1);
  for (int p = 0; p <= PMAX; ++p) {
    const bool active = layer ? (p >= 1) : true;
    const int T0 = 64 * p;
    const int T1 = layer ? 64 * p : 64 * (p - 6);

    // ---- gates: one poller wave hits MALL, others spin an LDS mailbox ----
    if (wid == 2) {
      if (lane < 2) {
        int tgt = lane ? T1 : T0;
        if (tgt > 0) {
          const int* cp = lane ? cnt1 : cnt0;
          int v;
          do { v = ld_flag(cp); } while (v < tgt);
          __hip_atomic_store(lane ? &g1 : &g0, v,
                             __ATOMIC_RELEASE, __HIP_MEMORY_SCOPE_WORKGROUP);
        }
      }
    } else {
      if (active) {
        if (layer == 0 || s == 0) spin_lds(&g0, T0);
        else                      spin_lds(&g1, T1);
      }
    }

    v4f ah = {0.f, 0.f, 0.f, 0.f}, al = {0.f, 0.f, 0.f, 0.f};
    float zpf[4];

    if (active) {
      // z0[p] issue (L0 s0) — drains inside the pipeline's waits
      if (layer == 0 && s == 0) {
        #pragma unroll
        for (int r = 0; r < 4; ++r)
          zpf[r] = z0[((size_t)(m * 16 + q4 + r) * S_ + p) * DH + rowW];
      }
      const unsigned short* hA;
      int koff;
      if (layer == 0) {
        hA = h0ring + (size_t)((p - 1) & RM) * SLOT_U + (size_t)rowA * 512;
        koff = s * 8;
      } else if (s == 0) {
        hA = h0ring + (size_t)((p - 1) & RM) * SLOT_U + (size_t)rowA * 512;
        koff = 0;
      } else {
        hA = h1ring + (size_t)((p - 2) & RM) * SLOT_U + (size_t)rowA * 512;
        koff = 0;
      }
      const unsigned short* lA = hA + LO_U;
      v8s hf[16], lf[16];

      if (layer == 0) {                  // 8 K-steps (16 loads)
        ISSUE(0); ISSUE(1); ISSUE(2); ISSUE(3);
        ISSUE(4); ISSUE(5); ISSUE(6); ISSUE(7);
        WAITN(8);
        MM(0); MM(1); MM(2); MM(3);
        WAITN(0);
        MM(4); MM(5); MM(6); MM(7);
      } else {                           // 16 K-steps (32 loads), 4-stage pipe
        ISSUE(0); ISSUE(1); ISSUE(2); ISSUE(3);
        ISSUE(4); ISSUE(5); ISSUE(6); ISSUE(7);
        WAITN(8);
        ISSUE(8); ISSUE(9); ISSUE(10); ISSUE(11); SB();
        MM(0); MM(1); MM(2); MM(3);
        WAITN(8);
        ISSUE(12); ISSUE(13); ISSUE(14); ISSUE(15); SB();
        MM(4); MM(5); MM(6); MM(7);
        WAITN(8);
        MM(8); MM(9); MM(10); MM(11);
        WAITN(0);
        MM(12); MM(13); MM(14); MM(15);
      }
      if (s == 1) lds_p[p & 1][(m * 2 + n) * 64 + lane] = ah + al;
    }
    __syncthreads();

    if (s == 0) {
      float hv4[4];
      if (active) {
        v4f other = lds_p[p & 1][(m * 2 + n) * 64 + lane];
        #pragma unroll
        for (int r = 0; r < 4; ++r) {
          float v = ah[r] + al[r] + other[r] + (layer ? biasv : zpf[r]);
          hv4[r] = fast_tanh(v);
        }
        unsigned short* dst = (layer == 0)
            ? h0ring + (size_t)(p & RM) * SLOT_U
            : h1ring + (size_t)((p - 1) & RM) * SLOT_U;
        #pragma unroll
        for (int r = 0; r < 4; ++r) {
          unsigned short hv = f2bf(hv4[r]);
          unsigned short lv = f2bf(hv4[r] - bf2f(hv));
          size_t off = (size_t)(m * 16 + q4 + r) * 512 + rowW;
          st16u(dst + off, hv);
          st16u(dst + off + LO_U, lv);
        }
      }
      wait_vm0();                                   // release: data before count
      if (lane == 0)
        __hip_atomic_fetch_add(cnt_own, 1, __ATOMIC_RELAXED,
                               __HIP_MEMORY_SCOPE_AGENT);
      if (active && layer == 1) {
        #pragma unroll
        for (int r = 0; r < 4; ++r)
          dout[((size_t)(m * 16 + q4 + r) * S_ + (p - 1)) * DH + rowW] = hv4[r];
      }
    }
  }
}

// ---------------------------------------------------------------------------
extern "C" void kernel_launch(void* const* d_in, const int* in_sizes, int n_in,
                              void* d_out, int out_size, void* d_ws, size_t ws_size,
                              hipStream_t stream) {
  const float* x      = (const float*)d_in[0];
  const float* hidden = (const float*)d_in[1];
  const float* w_ih   = (const float*)d_in[2];
  const float* w_hh   = (const float*)d_in[3];
  const float* b_ih   = (const float*)d_in[4];
  const float* b_hh   = (const float*)d_in[5];
  const float* w_out  = (const float*)d_in[6];
  const float* b_out  = (const float*)d_in[7];
  float* out = (float*)d_out;

  char* wsb = (char*)d_ws;
  int* cnt0              = (int*)(wsb + CNT0_OFF);
  int* cnt1              = (int*)(wsb + CNT1_OFF);
  float* bias            = (float*)(wsb + BIAS_OFF);
  unsigned short* h0ring = (unsigned short*)(wsb + H0_OFF);
  unsigned short* h1ring = (unsigned short*)(wsb + H1_OFF);
  unsigned short* woutbf = (unsigned short*)(wsb + WOUT_OFF);
  unsigned short* wih0bf = (unsigned short*)(wsb + WIH0_OFF);

  rnn_init<<<256, 256, 0, stream>>>(hidden, b_ih, b_hh, w_out, w_ih,
                                    cnt0, bias, h0ring, h1ring, woutbf, wih0bf);
  // Z0 = x @ w_ih0^T + (b_ih0 + b_hh0) -> d_out
  proj64<<<(B_ * S_) / 64, 512, 0, stream>>>(x, out, wih0bf, bias);
  rnn_phase2<<<32, 512, 0, stream>>>(out, w_ih, w_hh, bias,
                                     h0ring, h1ring, cnt0, cnt1, out);
  // out = h1 @ w_out^T + b_out (in place)
  proj64<<<(B_ * S_) / 64, 512, 0, stream>>>(out, out, woutbf, b_out);
}

// Round 4
// 9798.060 us; speedup vs baseline: 3.1566x; 2.0115x over previous
//
#include <hip/hip_runtime.h>

// ============================================================================
// 2-layer tanh RNN, B=32, S=2048, D=H=O=512.
//  r3: fused-layer persistent kernel. 16 WGs = 2 batch-halves x 8 feature
//      slices (64 feats). Each WG computes L0 step p and L1 step p-1, sharing
//      h0(p-1) A-frags between the w_hh0 and w_ih1 GEMMs. 8 waves = 8
//      K-eighths (no duplicate loads): coherent traffic 6MB->1MB per step.
//      K-reduction via dynamic-LDS partials; 4 finisher waves reduce+tanh+
//      store. Barrier: per-finisher flag lines (no RMW), one poller wave
//      reads 32 flags in one parallel load; batch-half groups independent.
// ============================================================================

typedef short v8s __attribute__((ext_vector_type(8)));
typedef int   v4i __attribute__((ext_vector_type(4)));
typedef float v4f __attribute__((ext_vector_type(4)));

#define B_  32
#define S_  2048
#define DH  512
#define RM  3                 // ring depth 4

// ws layout (bytes)
#define FLAGS_OFF 0                       // 64 flags x 16 dwords (64B apart)
#define BIAS_OFF  8192                    // [2][512] f32 (b_ih + b_hh)
#define H0_OFF    16384                   // 4 slots x 64KB (hi[32][512]+lo[32][512])
#define H1_OFF    (H0_OFF + 4 * 65536)
#define WOUT_OFF  (H1_OFF + 4 * 65536)    // w_out bf16 [512][512]
#define WIH0_OFF  (WOUT_OFF + 524288)     // w_ih[0] bf16 [512][512]
#define SLOT_U    32768                   // ushorts per ring slot (hi+lo)
#define LO_U      16384                   // lo-plane offset (ushorts)

#define PART_BYTES (8 * 3 * 4 * 64 * 16)  // 96KB partials

static __device__ __forceinline__ unsigned short f2bf(float f) {  // RNE
  unsigned int u = __builtin_bit_cast(unsigned int, f);
  u += 0x7fffu + ((u >> 16) & 1u);
  return (unsigned short)(u >> 16);
}
static __device__ __forceinline__ float bf2f(unsigned short h) {
  return __builtin_bit_cast(float, ((unsigned int)h) << 16);
}
static __device__ __forceinline__ v8s pack8(float4 f0, float4 f1) {
  v8s r;
  r[0] = (short)f2bf(f0.x); r[1] = (short)f2bf(f0.y);
  r[2] = (short)f2bf(f0.z); r[3] = (short)f2bf(f0.w);
  r[4] = (short)f2bf(f1.x); r[5] = (short)f2bf(f1.y);
  r[6] = (short)f2bf(f1.z); r[7] = (short)f2bf(f1.w);
  return r;
}
static __device__ __forceinline__ float fast_tanh(float v) {
  float c = fminf(15.f, fmaxf(-15.f, v));
  float e = __expf(2.f * c);
  return (e - 1.f) * __builtin_amdgcn_rcpf(e + 1.f);
}

// ---- coherent (cache-bypassing) and ordered-cached accessors ---------------
static __device__ __forceinline__ v8s ld16c(const void* p) {
  v4i r;
  asm volatile("global_load_dwordx4 %0, %1, off sc0 sc1"
               : "=v"(r) : "v"(p) : "memory");
  return __builtin_bit_cast(v8s, r);
}
static __device__ __forceinline__ float ld4(const void* p) {  // cached, ordered
  float r;
  asm volatile("global_load_dword %0, %1, off"
               : "=v"(r) : "v"(p) : "memory");
  return r;
}
static __device__ __forceinline__ void st16u(void* p, unsigned short v) {
  unsigned int vv = v;
  asm volatile("global_store_short %0, %1, off sc0 sc1"
               :: "v"(p), "v"(vv) : "memory");
}
static __device__ __forceinline__ void st32u(void* p, int v) {
  asm volatile("global_store_dword %0, %1, off sc0 sc1"
               :: "v"(p), "v"(v) : "memory");
}
static __device__ __forceinline__ int ld_flag(const int* p) {
  int r;
  asm volatile("global_load_dword %0, %1, off sc0 sc1\n\ts_waitcnt vmcnt(0)"
               : "=v"(r) : "v"(p) : "memory");
  return r;
}
static __device__ __forceinline__ void wait_vm0() {
  asm volatile("s_waitcnt vmcnt(0)" ::: "memory");
}
#define WAITN(N) do { asm volatile("s_waitcnt vmcnt(" #N ")" ::: "memory"); \
    __builtin_amdgcn_sched_barrier(0); } while (0)

// ---------------------------------------------------------------------------
__global__ void rnn_init(const float* __restrict__ hidden,
                         const float* __restrict__ b_ih,
                         const float* __restrict__ b_hh,
                         const float* __restrict__ w_out,
                         const float* __restrict__ w_ih,
                         int* __restrict__ flags,
                         float* __restrict__ bias,
                         unsigned short* __restrict__ h0ring,
                         unsigned short* __restrict__ h1ring,
                         unsigned short* __restrict__ woutbf,
                         unsigned short* __restrict__ wih0bf) {
  int i = blockIdx.x * blockDim.x + threadIdx.x;
  int nth = gridDim.x * blockDim.x;
  for (int t = i; t < 2048; t += nth) flags[t] = 0;
  for (int t = i; t < 1024; t += nth) bias[t] = b_ih[t] + b_hh[t];
  for (int t = i; t < 2 * B_ * DH; t += nth) {     // hidden -> ring slot 3
    int l = t >> 14;
    int off = t & 16383;
    float v = hidden[t];
    unsigned short hv = f2bf(v);
    unsigned short lv = f2bf(v - bf2f(hv));
    unsigned short* ring = l ? h1ring : h0ring;
    ring[3 * SLOT_U + off] = hv;
    ring[3 * SLOT_U + LO_U + off] = lv;
  }
  for (int t = i; t < 512 * 512; t += nth) {
    woutbf[t] = f2bf(w_out[t]);
    wih0bf[t] = f2bf(w_ih[t]);
  }
}

// ---------------------------------------------------------------------------
// Bulk projection: dst[r][:] = src[r][:] @ wb^T + bias (64 rows/WG, in-place ok)
__global__ __launch_bounds__(512) void proj64(
    const float* __restrict__ src,
    float* __restrict__ dst,
    const unsigned short* __restrict__ wb,
    const float* __restrict__ bias) {
  __shared__ unsigned short lds[64 * 512];
  const int tid = threadIdx.x;
  const int wid = tid >> 6;
  const int lane = tid & 63;
  const size_t row0 = (size_t)blockIdx.x * 64;

  #pragma unroll
  for (int it = 0; it < 8; ++it) {
    int c = it * 512 + tid;
    int row = c >> 6;
    int col8 = c & 63;
    const float4* s4 = (const float4*)(src + (row0 + row) * DH + col8 * 8);
    float4 f0 = s4[0], f1 = s4[1];
    v8s t = pack8(f0, f1);
    int byteoff = row * 1024 + ((col8 * 16) ^ ((row & 7) << 4));
    *(v8s*)((char*)lds + byteoff) = t;
  }
  __syncthreads();

  const int l15 = lane & 15;
  const int kq = (lane >> 4) * 8;

  for (int nt = wid; nt < 32; nt += 8) {
    v4f acc[4];
    #pragma unroll
    for (int mt = 0; mt < 4; ++mt) acc[mt] = (v4f){0.f, 0.f, 0.f, 0.f};
    const unsigned short* wr = wb + (size_t)(nt * 16 + l15) * 512;
    #pragma unroll
    for (int ks = 0; ks < 16; ++ks) {
      int kk = ks * 32 + kq;
      v8s bfrag = *(const v8s*)(wr + kk);
      #pragma unroll
      for (int mt = 0; mt < 4; ++mt) {
        int row = mt * 16 + l15;
        int byteoff = row * 1024 + ((kk * 2) ^ ((row & 7) << 4));
        v8s afrag = *(const v8s*)((char*)lds + byteoff);
        acc[mt] = __builtin_amdgcn_mfma_f32_16x16x32_bf16(afrag, bfrag, acc[mt], 0, 0, 0);
      }
    }
    float bo = bias[nt * 16 + l15];
    #pragma unroll
    for (int mt = 0; mt < 4; ++mt)
      #pragma unroll
      for (int r = 0; r < 4; ++r) {
        int row = mt * 16 + (lane >> 4) * 4 + r;
        int col = nt * 16 + l15;
        dst[(row0 + row) * DH + col] = acc[mt][r] + bo;
      }
  }
}

// ---------------------------------------------------------------------------
// Fused persistent kernel. wg = mh*8 + fs. mh: batch half (16 batches),
// fs: feature slice (64 feats, both layers). 8 waves = 8 K-eighths.
// Phase p: L0 computes h0(p) (p<2048), L1 computes h1(p-1) (p>=1).
__global__ __launch_bounds__(512) void rnn_fused(
    const float* __restrict__ z0,     // d_out: Z0 (overwritten by h1/dout)
    const float* __restrict__ w_ih,
    const float* __restrict__ w_hh,
    const float* __restrict__ bias,
    unsigned short* __restrict__ h0ring,
    unsigned short* __restrict__ h1ring,
    int* __restrict__ flags,
    float* __restrict__ dout) {
  extern __shared__ char smem[];
  v4f* part = (v4f*)smem;                            // [8][3][4][64]
  int* gmb  = (int*)(smem + PART_BYTES);             // mailbox

  const int wg = blockIdx.x;
  const int mh = wg >> 3;               // batch half
  const int fs = wg & 7;                // feature slice (64 feats)

  const int tid = threadIdx.x;
  const int wid = tid >> 6;             // K-eighth
  const int lane = tid & 63;
  const int l15 = lane & 15;
  const int kq = (lane >> 4) * 8;
  const int q4 = (lane >> 4) * 4;

  // ---- resident weights: wfrag[g][n][ks], g: {w_hh0, w_ih1, w_hh1} --------
  v8s wfrag[3][4][2];
  {
    const float* wsrcs[3] = { w_hh, w_ih + 512 * 512, w_hh + 512 * 512 };
    #pragma unroll
    for (int g = 0; g < 3; ++g)
      #pragma unroll
      for (int n = 0; n < 4; ++n)
        #pragma unroll
        for (int ks = 0; ks < 2; ++ks) {
          const float* srow = wsrcs[g] +
              (size_t)(fs * 64 + n * 16 + l15) * 512 + wid * 64 + ks * 32 + kq;
          wfrag[g][n][ks] = pack8(*(const float4*)srow, *(const float4*)(srow + 4));
        }
  }
  const int nf = wid;                   // finisher n-tile (wid<4)
  const float bias1v = bias[512 + fs * 64 + (nf & 3) * 16 + l15];

  // per-lane A-frag base offset (batch row x 512 + wave K base)
  const size_t abase = (size_t)(mh * 16 + l15) * 512 + wid * 64 + kq;
  // finisher store offsets: batch = mh*16+q4+r, feat = fs*64+nf*16+l15
  const int featf = fs * 64 + (nf & 3) * 16 + l15;

  // poller flag base (32 flags of own group, 64B apart)
  const int* fb = flags + (mh * 32 + (lane & 31)) * 16;
  int* const myflag = flags + (wg * 4 + (nf & 3)) * 16;

  if (tid == 0) *gmb = 0;
  __syncthreads();

  for (int p = 0; p <= S_; ++p) {
    // ---- gate: all own-group WGs finished phase p-1 ----------------------
    if (wid == 4) {
      int v;
      do { v = ld_flag(fb); } while (!__all(v >= p));
      __hip_atomic_store(gmb, p, __ATOMIC_RELEASE, __HIP_MEMORY_SCOPE_WORKGROUP);
    } else {
      while (__hip_atomic_load(gmb, __ATOMIC_ACQUIRE,
                               __HIP_MEMORY_SCOPE_WORKGROUP) < p) {}
    }

    // ---- A-frag loads (coherent) + z0 (cached, finishers) ----------------
    const unsigned short* h0b = h0ring + (size_t)((p - 1) & RM) * SLOT_U + abase;
    const unsigned short* h1b = h1ring + (size_t)((p - 2) & RM) * SLOT_U + abase;
    v8s a0h[2], a0l[2], a1h[2], a1l[2];
    a0h[0] = ld16c(h0b);           a0l[0] = ld16c(h0b + LO_U);
    a0h[1] = ld16c(h0b + 32);      a0l[1] = ld16c(h0b + 32 + LO_U);
    a1h[0] = ld16c(h1b);           a1l[0] = ld16c(h1b + LO_U);
    a1h[1] = ld16c(h1b + 32);      a1l[1] = ld16c(h1b + 32 + LO_U);

    float zp[4];
    if (wid < 4) {
      const int pz = (p < S_) ? p : (S_ - 1);
      #pragma unroll
      for (int r = 0; r < 4; ++r)
        zp[r] = ld4(z0 + ((size_t)(mh * 16 + q4 + r) * S_ + pz) * DH + featf);
    }

    v4f acc[3][4];
    #pragma unroll
    for (int g = 0; g < 3; ++g)
      #pragma unroll
      for (int n = 0; n < 4; ++n) acc[g][n] = (v4f){0.f, 0.f, 0.f, 0.f};

    if (wid < 4) { WAITN(8); } else { WAITN(4); }     // h0 frags ready
    #pragma unroll
    for (int ks = 0; ks < 2; ++ks)
      #pragma unroll
      for (int n = 0; n < 4; ++n) {
        acc[0][n] = __builtin_amdgcn_mfma_f32_16x16x32_bf16(a0h[ks], wfrag[0][n][ks], acc[0][n], 0, 0, 0);
        acc[1][n] = __builtin_amdgcn_mfma_f32_16x16x32_bf16(a0h[ks], wfrag[1][n][ks], acc[1][n], 0, 0, 0);
      }
    #pragma unroll
    for (int ks = 0; ks < 2; ++ks)
      #pragma unroll
      for (int n = 0; n < 4; ++n) {
        acc[0][n] = __builtin_amdgcn_mfma_f32_16x16x32_bf16(a0l[ks], wfrag[0][n][ks], acc[0][n], 0, 0, 0);
        acc[1][n] = __builtin_amdgcn_mfma_f32_16x16x32_bf16(a0l[ks], wfrag[1][n][ks], acc[1][n], 0, 0, 0);
      }
    if (wid < 4) { WAITN(4); } else { WAITN(0); }     // h1 frags ready
    #pragma unroll
    for (int ks = 0; ks < 2; ++ks)
      #pragma unroll
      for (int n = 0; n < 4; ++n) {
        acc[2][n] = __builtin_amdgcn_mfma_f32_16x16x32_bf16(a1h[ks], wfrag[2][n][ks], acc[2][n], 0, 0, 0);
        acc[2][n] = __builtin_amdgcn_mfma_f32_16x16x32_bf16(a1l[ks], wfrag[2][n][ks], acc[2][n], 0, 0, 0);
      }

    // ---- K-reduction partials -------------------------------------------
    #pragma unroll
    for (int g = 0; g < 3; ++g)
      #pragma unroll
      for (int n = 0; n < 4; ++n)
        part[((wid * 3 + g) * 4 + n) * 64 + lane] = acc[g][n];
    __syncthreads();

    // ---- finishers: reduce, tanh, store, flag ---------------------------
    if (wid < 4) {
      v4f s0 = {0.f,0.f,0.f,0.f}, s1 = {0.f,0.f,0.f,0.f}, s2 = {0.f,0.f,0.f,0.f};
      #pragma unroll
      for (int w = 0; w < 8; ++w) {
        s0 += part[((w * 3 + 0) * 4 + nf) * 64 + lane];
        s1 += part[((w * 3 + 1) * 4 + nf) * 64 + lane];
        s2 += part[((w * 3 + 2) * 4 + nf) * 64 + lane];
      }
      WAITN(0);                                       // zp ready
      float h0v[4], h1v[4];
      #pragma unroll
      for (int r = 0; r < 4; ++r) {
        h0v[r] = fast_tanh(zp[r] + s0[r]);
        h1v[r] = fast_tanh(s1[r] + s2[r] + bias1v);
      }
      if (p < S_) {                                   // store h0(p)
        unsigned short* dst = h0ring + (size_t)(p & RM) * SLOT_U;
        #pragma unroll
        for (int r = 0; r < 4; ++r) {
          unsigned short hv = f2bf(h0v[r]);
          unsigned short lv = f2bf(h0v[r] - bf2f(hv));
          size_t off = (size_t)(mh * 16 + q4 + r) * 512 + featf;
          st16u(dst + off, hv);
          st16u(dst + off + LO_U, lv);
        }
      }
      if (p >= 1) {                                   // store h1(p-1) + dout
        unsigned short* dst = h1ring + (size_t)((p - 1) & RM) * SLOT_U;
        #pragma unroll
        for (int r = 0; r < 4; ++r) {
          unsigned short hv = f2bf(h1v[r]);
          unsigned short lv = f2bf(h1v[r] - bf2f(hv));
          size_t off = (size_t)(mh * 16 + q4 + r) * 512 + featf;
          st16u(dst + off, hv);
          st16u(dst + off + LO_U, lv);
          dout[((size_t)(mh * 16 + q4 + r) * S_ + (p - 1)) * DH + featf] = h1v[r];
        }
      }
      wait_vm0();                                     // stores globally visible
      st32u(myflag, p + 1);                           // release
    }
  }
}

// ---------------------------------------------------------------------------
extern "C" void kernel_launch(void* const* d_in, const int* in_sizes, int n_in,
                              void* d_out, int out_size, void* d_ws, size_t ws_size,
                              hipStream_t stream) {
  const float* x      = (const float*)d_in[0];
  const float* hidden = (const float*)d_in[1];
  const float* w_ih   = (const float*)d_in[2];
  const float* w_hh   = (const float*)d_in[3];
  const float* b_ih   = (const float*)d_in[4];
  const float* b_hh   = (const float*)d_in[5];
  const float* w_out  = (const float*)d_in[6];
  const float* b_out  = (const float*)d_in[7];
  float* out = (float*)d_out;

  char* wsb = (char*)d_ws;
  int* flags             = (int*)(wsb + FLAGS_OFF);
  float* bias            = (float*)(wsb + BIAS_OFF);
  unsigned short* h0ring = (unsigned short*)(wsb + H0_OFF);
  unsigned short* h1ring = (unsigned short*)(wsb + H1_OFF);
  unsigned short* woutbf = (unsigned short*)(wsb + WOUT_OFF);
  unsigned short* wih0bf = (unsigned short*)(wsb + WIH0_OFF);

  rnn_init<<<256, 256, 0, stream>>>(hidden, b_ih, b_hh, w_out, w_ih,
                                    flags, bias, h0ring, h1ring, woutbf, wih0bf);
  // Z0 = x @ w_ih0^T + (b_ih0 + b_hh0) -> d_out
  proj64<<<(B_ * S_) / 64, 512, 0, stream>>>(x, out, wih0bf, bias);
  rnn_fused<<<16, 512, PART_BYTES + 16, stream>>>(out, w_ih, w_hh, bias,
                                                  h0ring, h1ring, flags, out);
  // out = h1 @ w_out^T + b_out (in place)
  proj64<<<(B_ * S_) / 64, 512, 0, stream>>>(out, out, woutbf, b_out);
}